// Round 7
// baseline (265.759 us; speedup 1.0000x reference)
//
#include <hip/hip_runtime.h>
#include <hip/hip_bf16.h>
#include <math.h>

#define NB 64        // B
#define NH 8         // H
#define NE 65536     // E
#define ND 256       // N2
#define IDX_STRIDE 2048
#define WSLICE 32    // keys per wave-slice (score/agg)
#define NWS 64       // wave-slices per b

// ============ prep: q = Wq gq + bq ; t2[b][d][h] = (Wk_h^T q_h)[d] ; c[h]=q_h.bk_h
__global__ __launch_bounds__(256) void prep_k(const float* __restrict__ gq,
    const float* __restrict__ Wq, const float* __restrict__ bq,
    const float* __restrict__ Wk, const float* __restrict__ bk,
    float* __restrict__ t2, float* __restrict__ c_ws)
{
  __shared__ float xs[ND];
  __shared__ float qs[ND];
  const int b = blockIdx.x;
  const int j = threadIdx.x;
  xs[j] = gq[(size_t)b * ND + j];
  __syncthreads();
  float acc = bq[j];
  const float4* wp = (const float4*)(Wq + (size_t)j * ND);
  #pragma unroll 8
  for (int k4 = 0; k4 < ND / 4; ++k4) {
    float4 w = wp[k4];
    float4 x = *(const float4*)&xs[k4 * 4];
    acc = fmaf(x.x, w.x, acc);
    acc = fmaf(x.y, w.y, acc);
    acc = fmaf(x.z, w.z, acc);
    acc = fmaf(x.w, w.w, acc);
  }
  qs[j] = acc;
  __syncthreads();
  float th[NH];
  #pragma unroll
  for (int h = 0; h < NH; ++h) th[h] = 0.f;
  #pragma unroll
  for (int h = 0; h < NH; ++h) {
    #pragma unroll 8
    for (int dd = 0; dd < 32; ++dd)
      th[h] = fmaf(qs[h * 32 + dd], Wk[(size_t)(h * 32 + dd) * ND + j], th[h]);
  }
  float* tp = t2 + ((size_t)b * ND + j) * NH;
  #pragma unroll
  for (int h = 0; h < NH; ++h) tp[h] = th[h];
  if (j < NH) {
    float c = 0.f;
    #pragma unroll
    for (int dd = 0; dd < 32; ++dd)
      c = fmaf(qs[j * 32 + dd], bk[j * 32 + dd], c);
    c_ws[b * NH + j] = c;
  }
}

// ============ bucket: stable stream-compaction, per-b index lists (validated)
__global__ __launch_bounds__(512) void bucket_k(const int* __restrict__ batch,
    int* __restrict__ idx, int* __restrict__ counts)
{
  __shared__ int wbase[8];
  __shared__ int running;
  const int b = blockIdx.x;
  const int tid = threadIdx.x;
  const int wid = tid >> 6, lane = tid & 63;
  const unsigned long long lt = (1ULL << lane) - 1ULL;
  if (tid == 0) running = 0;
  int* __restrict__ myidx = idx + b * IDX_STRIDE;

  for (int it = 0; it < NE / 2048; ++it) {
    const int e0 = it * 2048 + tid * 4;
    const int4 bt = *(const int4*)(batch + e0);
    const bool f[4] = {bt.x == b, bt.y == b, bt.z == b, bt.w == b};
    int rk[4];
    int wcnt = 0;
    #pragma unroll
    for (int u = 0; u < 4; ++u) {
      unsigned long long mk = __ballot(f[u]);
      rk[u] = wcnt + __popcll(mk & lt);
      wcnt += __popcll(mk);
    }
    __syncthreads();
    if (lane == 0) wbase[wid] = wcnt;
    __syncthreads();
    if (tid == 0) {
      int r = running;
      #pragma unroll
      for (int w = 0; w < 8; ++w) { int c = wbase[w]; wbase[w] = r; r += c; }
      running = r;
    }
    __syncthreads();
    const int base = wbase[wid];
    #pragma unroll
    for (int u = 0; u < 4; ++u) {
      const int p = base + rk[u];
      if (f[u] && p < IDX_STRIDE) myidx[p] = e0 + u;
    }
  }
  __syncthreads();
  if (tid == 0) counts[b] = running;
}

// ============ score: wave-autonomous, barrier-free. Wave = 32 keys of one b.
// s(e,h) = c[h] + sum_d t2[b][d][h] * lk[e][d]; lane owns dims [4l,4l+4).
__global__ __launch_bounds__(256) void score_k(const float* __restrict__ lk,
    const int* __restrict__ idx, const int* __restrict__ counts,
    const float* __restrict__ t2, const float* __restrict__ c_ws,
    float* __restrict__ score2)
{
  const int b = blockIdx.x >> 4;
  const int blk = blockIdx.x & 15;
  const int tid = threadIdx.x;
  const int wid = tid >> 6, lane = tid & 63;
  const int ws = blk * 4 + wid;                 // 0..63
  const int count = min(counts[b], IDX_STRIDE);
  const int j0 = ws * WSLICE;
  if (j0 >= count) return;                      // wave-uniform
  const int nk = min(WSLICE, count - j0);

  // t fragment in regs: t2s[i*8+h] = t2[b][lane*4+i][h]
  float t2s[32];
  {
    const float4* tp = (const float4*)(t2 + ((size_t)b * ND + lane * 4) * NH);
    #pragma unroll
    for (int k = 0; k < 8; ++k) {
      float4 v = tp[k];
      t2s[4 * k + 0] = v.x; t2s[4 * k + 1] = v.y;
      t2s[4 * k + 2] = v.z; t2s[4 * k + 3] = v.w;
    }
  }
  const float c8 = c_ws[b * NH + (lane & 7)];
  const int eidx = (lane < nk) ? idx[b * IDX_STRIDE + j0 + lane] : 0;

  for (int t = 0; t < nk; ++t) {
    const int e = __shfl(eidx, t);
    const float4 x4 = *(const float4*)(lk + (size_t)e * ND + lane * 4);
    float p[8];
    #pragma unroll
    for (int h = 0; h < 8; ++h)
      p[h] = fmaf(x4.x, t2s[0 * 8 + h], 0.f);
    #pragma unroll
    for (int h = 0; h < 8; ++h) {
      p[h] = fmaf(x4.y, t2s[1 * 8 + h], p[h]);
      p[h] = fmaf(x4.z, t2s[2 * 8 + h], p[h]);
      p[h] = fmaf(x4.w, t2s[3 * 8 + h], p[h]);
    }
    // intra-group-of-8 butterfly (all 8 values)
    #pragma unroll
    for (int h = 0; h < 8; ++h) {
      p[h] += __shfl_xor(p[h], 1);
      p[h] += __shfl_xor(p[h], 2);
      p[h] += __shfl_xor(p[h], 4);
    }
    // lane selects its h = lane&7 (compile-time cndmask chain, no scratch)
    float v = p[0];
    #pragma unroll
    for (int h = 1; h < 8; ++h) v = ((lane & 7) == h) ? p[h] : v;
    // cross-group reduce (one value)
    v += __shfl_xor(v, 8);
    v += __shfl_xor(v, 16);
    v += __shfl_xor(v, 32);
    v += c8;
    if (lane < 8)
      score2[((size_t)b * IDX_STRIDE + j0 + t) * NH + lane] = v;
  }
}

// ============ norm: per b, online (M,L) over score2 in one pass
__global__ __launch_bounds__(256) void norm_k(const float* __restrict__ score2,
    const int* __restrict__ counts, float* __restrict__ Minv_ws)
{
  __shared__ float rm[NH][264];
  __shared__ float rl[NH][264];
  const int b = blockIdx.x;
  const int tid = threadIdx.x;
  const int count = min(counts[b], IDX_STRIDE);

  float m8[NH], l8[NH];
  #pragma unroll
  for (int h = 0; h < NH; ++h) { m8[h] = -INFINITY; l8[h] = 0.f; }
  for (int j = tid; j < count; j += 256) {
    const float* sp = score2 + ((size_t)b * IDX_STRIDE + j) * NH;
    #pragma unroll
    for (int h = 0; h < NH; ++h) {
      const float s = sp[h];
      const float mn = fmaxf(m8[h], s);
      l8[h] = l8[h] * __expf(m8[h] - mn) + __expf(s - mn);
      m8[h] = mn;
    }
  }
  #pragma unroll
  for (int h = 0; h < NH; ++h) { rm[h][tid] = m8[h]; rl[h][tid] = l8[h]; }
  __syncthreads();
  if (tid < NH) {
    float M = -INFINITY, L = 0.f;
    for (int k = 0; k < 256; ++k) {
      const float m = rm[tid][k], l = rl[tid][k];
      const float Mn = fmaxf(M, m);
      if (Mn == -INFINITY) { L = 0.f; }
      else {
        L = L * __expf(M - Mn) + ((m == -INFINITY) ? 0.f : l * __expf(m - Mn));
      }
      M = Mn;
    }
    Minv_ws[((size_t)b * NH + tid) * 2 + 0] = M;
    Minv_ws[((size_t)b * NH + tid) * 2 + 1] = (L > 0.f) ? 1.f / L : 0.f;
  }
}

// ============ attn_write: dense zero stream + one barrier + L2-hot scatter
__global__ __launch_bounds__(256) void attn_write_k(
    const float* __restrict__ score2, const float* __restrict__ Minv_ws,
    const int* __restrict__ idx, const int* __restrict__ counts,
    float* __restrict__ attn_out)
{
  const int hb = blockIdx.x;          // h*64 + b
  const int h = hb >> 6, b = hb & 63;
  const int tid = threadIdx.x;
  const int count = min(counts[b], IDX_STRIDE);

  const float M = Minv_ws[((size_t)b * NH + h) * 2 + 0];
  const float inv = Minv_ws[((size_t)b * NH + h) * 2 + 1];

  float* __restrict__ arow = attn_out + (size_t)hb * NE;
  float4* __restrict__ arow4 = (float4*)arow;
  const float4 z4 = {0.f, 0.f, 0.f, 0.f};
  for (int c = tid; c < NE / 4; c += 256) arow4[c] = z4;
  __syncthreads();   // vmcnt(0) drain before barrier -> zeros committed

  const int* __restrict__ myidx = idx + b * IDX_STRIDE;
  for (int j = tid; j < count; j += 256)
    arow[myidx[j]] = __expf(score2[((size_t)b * IDX_STRIDE + j) * NH + h] - M) * inv;
}

// ============ agg: wave-autonomous over local_VALUE rows; per-wave partials
__global__ __launch_bounds__(256) void agg_k(const float* __restrict__ lv,
    const int* __restrict__ idx, const int* __restrict__ counts,
    const float* __restrict__ score2, const float* __restrict__ Minv_ws,
    float* __restrict__ pagg)
{
  const int b = blockIdx.x >> 4;
  const int blk = blockIdx.x & 15;
  const int tid = threadIdx.x;
  const int wid = tid >> 6, lane = tid & 63;
  const int ws = blk * 4 + wid;
  const int count = min(counts[b], IDX_STRIDE);
  const int j0 = ws * WSLICE;
  if (j0 >= count) return;
  const int nk = min(WSLICE, count - j0);

  float Mh[NH], Ih[NH];
  #pragma unroll
  for (int h = 0; h < NH; ++h) {
    Mh[h] = Minv_ws[((size_t)b * NH + h) * 2 + 0];
    Ih[h] = Minv_ws[((size_t)b * NH + h) * 2 + 1];
  }
  const int eidx = (lane < nk) ? idx[b * IDX_STRIDE + j0 + lane] : 0;

  float4 acc[NH];
  #pragma unroll
  for (int h = 0; h < NH; ++h) acc[h] = (float4){0.f, 0.f, 0.f, 0.f};

  for (int t = 0; t < nk; ++t) {
    const int e = __shfl(eidx, t);
    const float4 x4 = *(const float4*)(lv + (size_t)e * ND + lane * 4);
    const float* sp = score2 + ((size_t)b * IDX_STRIDE + j0 + t) * NH;
    #pragma unroll
    for (int h = 0; h < NH; ++h) {
      const float w = __expf(sp[h] - Mh[h]) * Ih[h];
      acc[h].x = fmaf(w, x4.x, acc[h].x);
      acc[h].y = fmaf(w, x4.y, acc[h].y);
      acc[h].z = fmaf(w, x4.z, acc[h].z);
      acc[h].w = fmaf(w, x4.w, acc[h].w);
    }
  }

  float* pb = pagg + (((size_t)b * NWS + ws) * NH) * ND;
  #pragma unroll
  for (int h = 0; h < NH; ++h)
    *(float4*)(pb + h * ND + lane * 4) = acc[h];
}

// ============ final: sum used wave-slices, apply Wv (+bv), then Wo (+bo)
__global__ __launch_bounds__(256) void final_k(const float* __restrict__ pagg,
    const int* __restrict__ counts, const float* __restrict__ Wv,
    const float* __restrict__ bv, const float* __restrict__ Wo,
    const float* __restrict__ bo, float* __restrict__ xout)
{
  __shared__ float agg[NH][260];
  __shared__ float opre[ND];
  const int b = blockIdx.x;
  const int tid = threadIdx.x;
  const int count = min(counts[b], IDX_STRIDE);
  const int nsl = min((count + WSLICE - 1) / WSLICE, NWS);

  #pragma unroll
  for (int h = 0; h < NH; ++h) {
    float a = 0.f;
    for (int s = 0; s < nsl; ++s)
      a += pagg[(((size_t)b * NWS + s) * NH + h) * ND + tid];
    agg[h][tid] = a;
  }
  const float ind = (count > 0) ? 1.f : 0.f;
  __syncthreads();

  {
    const int h = tid >> 5;
    float acc = bv[tid] * ind;
    const float4* wp = (const float4*)(Wv + (size_t)tid * ND);
    #pragma unroll 8
    for (int d4 = 0; d4 < ND / 4; ++d4) {
      float4 w = wp[d4];
      float4 g = *(const float4*)&agg[h][4 * d4];
      acc = fmaf(w.x, g.x, acc);
      acc = fmaf(w.y, g.y, acc);
      acc = fmaf(w.z, g.z, acc);
      acc = fmaf(w.w, g.w, acc);
    }
    opre[tid] = acc;
  }
  __syncthreads();
  {
    float acc = bo[tid];
    const float4* wp = (const float4*)(Wo + (size_t)tid * ND);
    #pragma unroll 8
    for (int d4 = 0; d4 < ND / 4; ++d4) {
      float4 w = wp[d4];
      float4 g = *(const float4*)&opre[4 * d4];
      acc = fmaf(w.x, g.x, acc);
      acc = fmaf(w.y, g.y, acc);
      acc = fmaf(w.z, g.z, acc);
      acc = fmaf(w.w, g.w, acc);
    }
    xout[(size_t)b * ND + tid] = acc;
  }
}

extern "C" void kernel_launch(void* const* d_in, const int* in_sizes, int n_in,
                              void* d_out, int out_size, void* d_ws, size_t ws_size,
                              hipStream_t stream)
{
  const float* gq   = (const float*)d_in[0];
  const float* lk   = (const float*)d_in[1];
  const float* lv   = (const float*)d_in[2];
  const int*  batch = (const int*)d_in[3];
  const float* Wq = (const float*)d_in[4];
  const float* bq = (const float*)d_in[5];
  const float* Wk = (const float*)d_in[6];
  const float* bk = (const float*)d_in[7];
  const float* Wv = (const float*)d_in[8];
  const float* bv = (const float*)d_in[9];
  const float* Wo = (const float*)d_in[10];
  const float* bo = (const float*)d_in[11];

  float* xout = (float*)d_out;                          // [64,256]
  float* attn_out = xout + (size_t)NB * ND;             // [H,B,E]

  float* t2      = (float*)d_ws;                                    // 64*256*8
  float* c_ws    = t2 + (size_t)NB * ND * NH;                       // 512
  float* score2  = c_ws + (size_t)NB * NH;                          // 64*2048*8
  float* Minv_ws = score2 + (size_t)NB * IDX_STRIDE * NH;           // 1024
  float* pagg    = Minv_ws + (size_t)NB * NH * 2;                   // 64*64*8*256
  int*   idx     = (int*)(pagg + (size_t)NB * NWS * NH * ND);       // 64*2048
  int*   counts  = idx + (size_t)NB * IDX_STRIDE;                   // 64

  prep_k<<<NB, ND, 0, stream>>>(gq, Wq, bq, Wk, bk, t2, c_ws);
  bucket_k<<<NB, 512, 0, stream>>>(batch, idx, counts);
  score_k<<<NB * 16, 256, 0, stream>>>(lk, idx, counts, t2, c_ws, score2);
  norm_k<<<NB, 256, 0, stream>>>(score2, counts, Minv_ws);
  attn_write_k<<<NH * NB, 256, 0, stream>>>(score2, Minv_ws, idx, counts, attn_out);
  agg_k<<<NB * 16, 256, 0, stream>>>(lv, idx, counts, score2, Minv_ws, pagg);
  final_k<<<NB, 256, 0, stream>>>(pagg, counts, Wv, bv, Wo, bo, xout);
}

// Round 8
// 212.673 us; speedup vs baseline: 1.2496x; 1.2496x over previous
//
#include <hip/hip_runtime.h>
#include <hip/hip_bf16.h>
#include <math.h>

#define NB 64        // B
#define NH 8         // H
#define NE 65536     // E
#define ND 256       // N2
#define IDX_STRIDE 2048
#define WSLICE 32    // keys per wave-slice (score/agg)
#define NPB 16       // agg partials per b (one per agg block of 128 keys)

// ============ prep: q = Wq gq + bq ; t2[b][d][h] = (Wk_h^T q_h)[d] ; c[h]=q_h.bk_h
__global__ __launch_bounds__(256) void prep_k(const float* __restrict__ gq,
    const float* __restrict__ Wq, const float* __restrict__ bq,
    const float* __restrict__ Wk, const float* __restrict__ bk,
    float* __restrict__ t2, float* __restrict__ c_ws)
{
  __shared__ float xs[ND];
  __shared__ float qs[ND];
  const int b = blockIdx.x;
  const int j = threadIdx.x;
  xs[j] = gq[(size_t)b * ND + j];
  __syncthreads();
  float acc = bq[j];
  const float4* wp = (const float4*)(Wq + (size_t)j * ND);
  #pragma unroll 8
  for (int k4 = 0; k4 < ND / 4; ++k4) {
    float4 w = wp[k4];
    float4 x = *(const float4*)&xs[k4 * 4];
    acc = fmaf(x.x, w.x, acc);
    acc = fmaf(x.y, w.y, acc);
    acc = fmaf(x.z, w.z, acc);
    acc = fmaf(x.w, w.w, acc);
  }
  qs[j] = acc;
  __syncthreads();
  float th[NH];
  #pragma unroll
  for (int h = 0; h < NH; ++h) th[h] = 0.f;
  #pragma unroll
  for (int h = 0; h < NH; ++h) {
    #pragma unroll 8
    for (int dd = 0; dd < 32; ++dd)
      th[h] = fmaf(qs[h * 32 + dd], Wk[(size_t)(h * 32 + dd) * ND + j], th[h]);
  }
  float* tp = t2 + ((size_t)b * ND + j) * NH;
  #pragma unroll
  for (int h = 0; h < NH; ++h) tp[h] = th[h];
  if (j < NH) {
    float c = 0.f;
    #pragma unroll
    for (int dd = 0; dd < 32; ++dd)
      c = fmaf(qs[j * 32 + dd], bk[j * 32 + dd], c);
    c_ws[b * NH + j] = c;
  }
}

// ============ bucket: stable stream-compaction, per-b index lists (validated)
__global__ __launch_bounds__(512) void bucket_k(const int* __restrict__ batch,
    int* __restrict__ idx, int* __restrict__ counts)
{
  __shared__ int wbase[8];
  __shared__ int running;
  const int b = blockIdx.x;
  const int tid = threadIdx.x;
  const int wid = tid >> 6, lane = tid & 63;
  const unsigned long long lt = (1ULL << lane) - 1ULL;
  if (tid == 0) running = 0;
  int* __restrict__ myidx = idx + b * IDX_STRIDE;

  for (int it = 0; it < NE / 2048; ++it) {
    const int e0 = it * 2048 + tid * 4;
    const int4 bt = *(const int4*)(batch + e0);
    const bool f[4] = {bt.x == b, bt.y == b, bt.z == b, bt.w == b};
    int rk[4];
    int wcnt = 0;
    #pragma unroll
    for (int u = 0; u < 4; ++u) {
      unsigned long long mk = __ballot(f[u]);
      rk[u] = wcnt + __popcll(mk & lt);
      wcnt += __popcll(mk);
    }
    __syncthreads();
    if (lane == 0) wbase[wid] = wcnt;
    __syncthreads();
    if (tid == 0) {
      int r = running;
      #pragma unroll
      for (int w = 0; w < 8; ++w) { int c = wbase[w]; wbase[w] = r; r += c; }
      running = r;
    }
    __syncthreads();
    const int base = wbase[wid];
    #pragma unroll
    for (int u = 0; u < 4; ++u) {
      const int p = base + rk[u];
      if (f[u] && p < IDX_STRIDE) myidx[p] = e0 + u;
    }
  }
  __syncthreads();
  if (tid == 0) counts[b] = running;
}

// ============ score: wave-autonomous, barrier-free. Wave = 32 keys of one b.
__global__ __launch_bounds__(256) void score_k(const float* __restrict__ lk,
    const int* __restrict__ idx, const int* __restrict__ counts,
    const float* __restrict__ t2, const float* __restrict__ c_ws,
    float* __restrict__ score2)
{
  const int b = blockIdx.x >> 4;
  const int blk = blockIdx.x & 15;
  const int tid = threadIdx.x;
  const int wid = tid >> 6, lane = tid & 63;
  const int ws = blk * 4 + wid;                 // 0..63
  const int count = min(counts[b], IDX_STRIDE);
  const int j0 = ws * WSLICE;
  if (j0 >= count) return;                      // wave-uniform
  const int nk = min(WSLICE, count - j0);

  float t2s[32];
  {
    const float4* tp = (const float4*)(t2 + ((size_t)b * ND + lane * 4) * NH);
    #pragma unroll
    for (int k = 0; k < 8; ++k) {
      float4 v = tp[k];
      t2s[4 * k + 0] = v.x; t2s[4 * k + 1] = v.y;
      t2s[4 * k + 2] = v.z; t2s[4 * k + 3] = v.w;
    }
  }
  const float c8 = c_ws[b * NH + (lane & 7)];
  const int eidx = (lane < nk) ? idx[b * IDX_STRIDE + j0 + lane] : 0;

  for (int t = 0; t < nk; ++t) {
    const int e = __shfl(eidx, t);
    const float4 x4 = *(const float4*)(lk + (size_t)e * ND + lane * 4);
    float p[8];
    #pragma unroll
    for (int h = 0; h < 8; ++h)
      p[h] = fmaf(x4.x, t2s[0 * 8 + h], 0.f);
    #pragma unroll
    for (int h = 0; h < 8; ++h) {
      p[h] = fmaf(x4.y, t2s[1 * 8 + h], p[h]);
      p[h] = fmaf(x4.z, t2s[2 * 8 + h], p[h]);
      p[h] = fmaf(x4.w, t2s[3 * 8 + h], p[h]);
    }
    #pragma unroll
    for (int h = 0; h < 8; ++h) {
      p[h] += __shfl_xor(p[h], 1);
      p[h] += __shfl_xor(p[h], 2);
      p[h] += __shfl_xor(p[h], 4);
    }
    float v = p[0];
    #pragma unroll
    for (int h = 1; h < 8; ++h) v = ((lane & 7) == h) ? p[h] : v;
    v += __shfl_xor(v, 8);
    v += __shfl_xor(v, 16);
    v += __shfl_xor(v, 32);
    v += c8;
    if (lane < 8)
      score2[((size_t)b * IDX_STRIDE + j0 + t) * NH + lane] = v;
  }
}

// ============ norm: per b, online (M,L) over score2 in one pass
__global__ __launch_bounds__(256) void norm_k(const float* __restrict__ score2,
    const int* __restrict__ counts, float* __restrict__ Minv_ws)
{
  __shared__ float rm[NH][264];
  __shared__ float rl[NH][264];
  const int b = blockIdx.x;
  const int tid = threadIdx.x;
  const int count = min(counts[b], IDX_STRIDE);

  float m8[NH], l8[NH];
  #pragma unroll
  for (int h = 0; h < NH; ++h) { m8[h] = -INFINITY; l8[h] = 0.f; }
  for (int j = tid; j < count; j += 256) {
    const float* sp = score2 + ((size_t)b * IDX_STRIDE + j) * NH;
    #pragma unroll
    for (int h = 0; h < NH; ++h) {
      const float s = sp[h];
      const float mn = fmaxf(m8[h], s);
      l8[h] = l8[h] * __expf(m8[h] - mn) + __expf(s - mn);
      m8[h] = mn;
    }
  }
  #pragma unroll
  for (int h = 0; h < NH; ++h) { rm[h][tid] = m8[h]; rl[h][tid] = l8[h]; }
  __syncthreads();
  if (tid < NH) {
    float M = -INFINITY, L = 0.f;
    for (int k = 0; k < 256; ++k) {
      const float m = rm[tid][k], l = rl[tid][k];
      const float Mn = fmaxf(M, m);
      if (Mn == -INFINITY) { L = 0.f; }
      else {
        L = L * __expf(M - Mn) + ((m == -INFINITY) ? 0.f : l * __expf(m - Mn));
      }
      M = Mn;
    }
    Minv_ws[((size_t)b * NH + tid) * 2 + 0] = M;
    Minv_ws[((size_t)b * NH + tid) * 2 + 1] = (L > 0.f) ? 1.f / L : 0.f;
  }
}

// ============ attn_write: dense zero stream + one barrier + L2-hot scatter
__global__ __launch_bounds__(256) void attn_write_k(
    const float* __restrict__ score2, const float* __restrict__ Minv_ws,
    const int* __restrict__ idx, const int* __restrict__ counts,
    float* __restrict__ attn_out)
{
  const int hb = blockIdx.x;          // h*64 + b
  const int h = hb >> 6, b = hb & 63;
  const int tid = threadIdx.x;
  const int count = min(counts[b], IDX_STRIDE);

  const float M = Minv_ws[((size_t)b * NH + h) * 2 + 0];
  const float inv = Minv_ws[((size_t)b * NH + h) * 2 + 1];

  float* __restrict__ arow = attn_out + (size_t)hb * NE;
  float4* __restrict__ arow4 = (float4*)arow;
  const float4 z4 = {0.f, 0.f, 0.f, 0.f};
  for (int c = tid; c < NE / 4; c += 256) arow4[c] = z4;
  __syncthreads();   // vmcnt(0) drain before barrier -> zeros committed

  const int* __restrict__ myidx = idx + b * IDX_STRIDE;
  for (int j = tid; j < count; j += 256)
    arow[myidx[j]] = __expf(score2[((size_t)b * IDX_STRIDE + j) * NH + h] - M) * inv;
}

// ============ agg: wave-autonomous over local_VALUE rows; block-level partial
// (4 waves reduced via LDS -> one 8x256 partial per block, NPB=16 per b)
__global__ __launch_bounds__(256) void agg_k(const float* __restrict__ lv,
    const int* __restrict__ idx, const int* __restrict__ counts,
    const float* __restrict__ score2, const float* __restrict__ Minv_ws,
    float* __restrict__ pagg)
{
  __shared__ float s_red[3][NH][260];
  const int b = blockIdx.x >> 4;
  const int blk = blockIdx.x & 15;
  const int tid = threadIdx.x;
  const int wid = tid >> 6, lane = tid & 63;
  const int count = min(counts[b], IDX_STRIDE);
  if (blk * 128 >= count) return;               // whole-block uniform exit

  const int j0 = (blk * 4 + wid) * WSLICE;
  const int nk = min(WSLICE, count - j0);       // may be <= 0

  float4 acc[NH];
  #pragma unroll
  for (int h = 0; h < NH; ++h) acc[h] = (float4){0.f, 0.f, 0.f, 0.f};

  if (nk > 0) {
    float Mh[NH], Ih[NH];
    #pragma unroll
    for (int h = 0; h < NH; ++h) {
      Mh[h] = Minv_ws[((size_t)b * NH + h) * 2 + 0];
      Ih[h] = Minv_ws[((size_t)b * NH + h) * 2 + 1];
    }
    const int eidx = (lane < nk) ? idx[b * IDX_STRIDE + j0 + lane] : 0;
    for (int t = 0; t < nk; ++t) {
      const int e = __shfl(eidx, t);
      const float4 x4 = *(const float4*)(lv + (size_t)e * ND + lane * 4);
      const float* sp = score2 + ((size_t)b * IDX_STRIDE + j0 + t) * NH;
      #pragma unroll
      for (int h = 0; h < NH; ++h) {
        const float w = __expf(sp[h] - Mh[h]) * Ih[h];
        acc[h].x = fmaf(w, x4.x, acc[h].x);
        acc[h].y = fmaf(w, x4.y, acc[h].y);
        acc[h].z = fmaf(w, x4.z, acc[h].z);
        acc[h].w = fmaf(w, x4.w, acc[h].w);
      }
    }
  }

  if (wid != 0) {
    #pragma unroll
    for (int h = 0; h < NH; ++h)
      *(float4*)&s_red[wid - 1][h][lane * 4] = acc[h];
  }
  __syncthreads();
  if (wid == 0) {
    #pragma unroll
    for (int h = 0; h < NH; ++h) {
      #pragma unroll
      for (int w = 0; w < 3; ++w) {
        const float4 r = *(const float4*)&s_red[w][h][lane * 4];
        acc[h].x += r.x; acc[h].y += r.y; acc[h].z += r.z; acc[h].w += r.w;
      }
    }
    float* pb = pagg + (((size_t)b * NPB + blk) * NH) * ND;
    #pragma unroll
    for (int h = 0; h < NH; ++h)
      *(float4*)(pb + h * ND + lane * 4) = acc[h];
  }
}

// ============ final: sum used block-partials, apply Wv (+bv), then Wo (+bo)
__global__ __launch_bounds__(256) void final_k(const float* __restrict__ pagg,
    const int* __restrict__ counts, const float* __restrict__ Wv,
    const float* __restrict__ bv, const float* __restrict__ Wo,
    const float* __restrict__ bo, float* __restrict__ xout)
{
  __shared__ float agg[NH][260];
  __shared__ float opre[ND];
  const int b = blockIdx.x;
  const int tid = threadIdx.x;
  const int count = min(counts[b], IDX_STRIDE);
  const int nblk = min((count + 127) / 128, NPB);

  #pragma unroll
  for (int h = 0; h < NH; ++h) {
    float a = 0.f;
    for (int s = 0; s < nblk; ++s)
      a += pagg[(((size_t)b * NPB + s) * NH + h) * ND + tid];
    agg[h][tid] = a;
  }
  const float ind = (count > 0) ? 1.f : 0.f;
  __syncthreads();

  {
    const int h = tid >> 5;
    float acc = bv[tid] * ind;
    const float4* wp = (const float4*)(Wv + (size_t)tid * ND);
    #pragma unroll 8
    for (int d4 = 0; d4 < ND / 4; ++d4) {
      float4 w = wp[d4];
      float4 g = *(const float4*)&agg[h][4 * d4];
      acc = fmaf(w.x, g.x, acc);
      acc = fmaf(w.y, g.y, acc);
      acc = fmaf(w.z, g.z, acc);
      acc = fmaf(w.w, g.w, acc);
    }
    opre[tid] = acc;
  }
  __syncthreads();
  {
    float acc = bo[tid];
    const float4* wp = (const float4*)(Wo + (size_t)tid * ND);
    #pragma unroll 8
    for (int d4 = 0; d4 < ND / 4; ++d4) {
      float4 w = wp[d4];
      float4 g = *(const float4*)&opre[4 * d4];
      acc = fmaf(w.x, g.x, acc);
      acc = fmaf(w.y, g.y, acc);
      acc = fmaf(w.z, g.z, acc);
      acc = fmaf(w.w, g.w, acc);
    }
    xout[(size_t)b * ND + tid] = acc;
  }
}

extern "C" void kernel_launch(void* const* d_in, const int* in_sizes, int n_in,
                              void* d_out, int out_size, void* d_ws, size_t ws_size,
                              hipStream_t stream)
{
  const float* gq   = (const float*)d_in[0];
  const float* lk   = (const float*)d_in[1];
  const float* lv   = (const float*)d_in[2];
  const int*  batch = (const int*)d_in[3];
  const float* Wq = (const float*)d_in[4];
  const float* bq = (const float*)d_in[5];
  const float* Wk = (const float*)d_in[6];
  const float* bk = (const float*)d_in[7];
  const float* Wv = (const float*)d_in[8];
  const float* bv = (const float*)d_in[9];
  const float* Wo = (const float*)d_in[10];
  const float* bo = (const float*)d_in[11];

  float* xout = (float*)d_out;                          // [64,256]
  float* attn_out = xout + (size_t)NB * ND;             // [H,B,E]

  float* t2      = (float*)d_ws;                                    // 64*256*8
  float* c_ws    = t2 + (size_t)NB * ND * NH;                       // 512
  float* score2  = c_ws + (size_t)NB * NH;                          // 64*2048*8
  float* Minv_ws = score2 + (size_t)NB * IDX_STRIDE * NH;           // 1024
  float* pagg    = Minv_ws + (size_t)NB * NH * 2;                   // 64*16*8*256
  int*   idx     = (int*)(pagg + (size_t)NB * NPB * NH * ND);       // 64*2048
  int*   counts  = idx + (size_t)NB * IDX_STRIDE;                   // 64

  prep_k<<<NB, ND, 0, stream>>>(gq, Wq, bq, Wk, bk, t2, c_ws);
  bucket_k<<<NB, 512, 0, stream>>>(batch, idx, counts);
  score_k<<<NB * 16, 256, 0, stream>>>(lk, idx, counts, t2, c_ws, score2);
  norm_k<<<NB, 256, 0, stream>>>(score2, counts, Minv_ws);
  attn_write_k<<<NH * NB, 256, 0, stream>>>(score2, Minv_ws, idx, counts, attn_out);
  agg_k<<<NB * 16, 256, 0, stream>>>(lv, idx, counts, score2, Minv_ws, pagg);
  final_k<<<NB, 256, 0, stream>>>(pagg, counts, Wv, bv, Wo, bo, xout);
}

// Round 9
// 196.959 us; speedup vs baseline: 1.3493x; 1.0798x over previous
//
#include <hip/hip_runtime.h>
#include <hip/hip_bf16.h>
#include <math.h>

#define NB 64        // B
#define NH 8         // H
#define NE 65536     // E
#define ND 256       // N2
#define IDX_STRIDE 2048
#define WSL_S 16     // keys per wave-slice in score (128 slices/b)
#define NSL 128      // score slices per b
#define WSLICE 32    // keys per wave in agg
#define NPB 16       // agg partials per b (blocks of 128 keys)

// ============ prep: q = Wq gq + bq ; t2[b][d][h] = (Wk_h^T q_h)[d] ; c[h]=q_h.bk_h
__global__ __launch_bounds__(256) void prep_k(const float* __restrict__ gq,
    const float* __restrict__ Wq, const float* __restrict__ bq,
    const float* __restrict__ Wk, const float* __restrict__ bk,
    float* __restrict__ t2, float* __restrict__ c_ws)
{
  __shared__ float xs[ND];
  __shared__ float qs[ND];
  const int b = blockIdx.x;
  const int j = threadIdx.x;
  xs[j] = gq[(size_t)b * ND + j];
  __syncthreads();
  float acc = bq[j];
  const float4* wp = (const float4*)(Wq + (size_t)j * ND);
  #pragma unroll 8
  for (int k4 = 0; k4 < ND / 4; ++k4) {
    float4 w = wp[k4];
    float4 x = *(const float4*)&xs[k4 * 4];
    acc = fmaf(x.x, w.x, acc);
    acc = fmaf(x.y, w.y, acc);
    acc = fmaf(x.z, w.z, acc);
    acc = fmaf(x.w, w.w, acc);
  }
  qs[j] = acc;
  __syncthreads();
  float th[NH];
  #pragma unroll
  for (int h = 0; h < NH; ++h) th[h] = 0.f;
  #pragma unroll
  for (int h = 0; h < NH; ++h) {
    #pragma unroll 8
    for (int dd = 0; dd < 32; ++dd)
      th[h] = fmaf(qs[h * 32 + dd], Wk[(size_t)(h * 32 + dd) * ND + j], th[h]);
  }
  float* tp = t2 + ((size_t)b * ND + j) * NH;
  #pragma unroll
  for (int h = 0; h < NH; ++h) tp[h] = th[h];
  if (j < NH) {
    float c = 0.f;
    #pragma unroll
    for (int dd = 0; dd < 32; ++dd)
      c = fmaf(qs[j * 32 + dd], bk[j * 32 + dd], c);
    c_ws[b * NH + j] = c;
  }
}

// ============ bucket: thread-owns-256-contiguous-keys + one block scan.
// Output is globally sorted (thread ranges contiguous, within-thread ordered).
__global__ __launch_bounds__(256) void bucket_k(const int* __restrict__ batch,
    int* __restrict__ idx, int* __restrict__ counts)
{
  __shared__ int sc[256];
  const int b = blockIdx.x;
  const int tid = threadIdx.x;
  const int4* b4 = (const int4*)batch;

  int c = 0;
  #pragma unroll 4
  for (int i = 0; i < 64; ++i) {
    const int4 v = b4[tid * 64 + i];
    c += (v.x == b) + (v.y == b) + (v.z == b) + (v.w == b);
  }
  sc[tid] = c;
  __syncthreads();
  // inclusive Hillis-Steele scan
  for (int s = 1; s < 256; s <<= 1) {
    const int t = (tid >= s) ? sc[tid - s] : 0;
    __syncthreads();
    sc[tid] += t;
    __syncthreads();
  }
  int pos = sc[tid] - c;                 // exclusive prefix
  int* __restrict__ myidx = idx + b * IDX_STRIDE;
  #pragma unroll 4
  for (int i = 0; i < 64; ++i) {
    const int4 v = b4[tid * 64 + i];
    const int e0 = tid * 256 + i * 4;
    if (v.x == b) { if (pos < IDX_STRIDE) myidx[pos] = e0 + 0; ++pos; }
    if (v.y == b) { if (pos < IDX_STRIDE) myidx[pos] = e0 + 1; ++pos; }
    if (v.z == b) { if (pos < IDX_STRIDE) myidx[pos] = e0 + 2; ++pos; }
    if (v.w == b) { if (pos < IDX_STRIDE) myidx[pos] = e0 + 3; ++pos; }
  }
  if (tid == 255) counts[b] = sc[255];
}

// ============ score: wave-autonomous, 16 keys/wave, fused per-slice (m,l)
__global__ __launch_bounds__(256) void score_k(const float* __restrict__ lk,
    const int* __restrict__ idx, const int* __restrict__ counts,
    const float* __restrict__ t2, const float* __restrict__ c_ws,
    float* __restrict__ score2, float* __restrict__ ml_ws)
{
  const int b = blockIdx.x >> 5;              // 32 blocks per b
  const int blk = blockIdx.x & 31;
  const int tid = threadIdx.x;
  const int wid = tid >> 6, lane = tid & 63;
  const int ws = blk * 4 + wid;               // 0..127
  const int count = min(counts[b], IDX_STRIDE);
  const int j0 = ws * WSL_S;
  if (j0 >= count) return;                    // wave-uniform
  const int nk = min(WSL_S, count - j0);

  float t2s[32];
  {
    const float4* tp = (const float4*)(t2 + ((size_t)b * ND + lane * 4) * NH);
    #pragma unroll
    for (int k = 0; k < 8; ++k) {
      float4 v = tp[k];
      t2s[4 * k + 0] = v.x; t2s[4 * k + 1] = v.y;
      t2s[4 * k + 2] = v.z; t2s[4 * k + 3] = v.w;
    }
  }
  const float c8 = c_ws[b * NH + (lane & 7)];
  const int eidx = (lane < nk) ? idx[b * IDX_STRIDE + j0 + lane] : 0;

  float m = -INFINITY, l = 0.f;
  #pragma unroll 2
  for (int t = 0; t < nk; ++t) {
    const int e = __shfl(eidx, t);
    const float4 x4 = *(const float4*)(lk + (size_t)e * ND + lane * 4);
    float p[8];
    #pragma unroll
    for (int h = 0; h < 8; ++h)
      p[h] = fmaf(x4.x, t2s[0 * 8 + h], 0.f);
    #pragma unroll
    for (int h = 0; h < 8; ++h) {
      p[h] = fmaf(x4.y, t2s[1 * 8 + h], p[h]);
      p[h] = fmaf(x4.z, t2s[2 * 8 + h], p[h]);
      p[h] = fmaf(x4.w, t2s[3 * 8 + h], p[h]);
    }
    #pragma unroll
    for (int h = 0; h < 8; ++h) {
      p[h] += __shfl_xor(p[h], 1);
      p[h] += __shfl_xor(p[h], 2);
      p[h] += __shfl_xor(p[h], 4);
    }
    float v = p[0];
    #pragma unroll
    for (int h = 1; h < 8; ++h) v = ((lane & 7) == h) ? p[h] : v;
    v += __shfl_xor(v, 8);
    v += __shfl_xor(v, 16);
    v += __shfl_xor(v, 32);
    v += c8;                                  // every lane: s for h=lane&7
    if (lane < 8)
      score2[((size_t)b * IDX_STRIDE + j0 + t) * NH + lane] = v;
    const float mn = fmaxf(m, v);
    l = l * __expf(m - mn) + __expf(v - mn);
    m = mn;
  }
  if (lane < 8) {
    ml_ws[(((size_t)b * NSL + ws) * NH + lane) * 2 + 0] = m;
    ml_ws[(((size_t)b * NSL + ws) * NH + lane) * 2 + 1] = l;
  }
}

// ============ attn_write: per (h,b): combine (m,l), emit compact w2,
// dense-zero the attn row, one barrier, L2-hot scatter.
__global__ __launch_bounds__(256) void attn_write_k(
    const float* __restrict__ score2, const float* __restrict__ ml_ws,
    const int* __restrict__ idx, const int* __restrict__ counts,
    float* __restrict__ w2, float* __restrict__ attn_out)
{
  __shared__ float s_mw[2][2];
  __shared__ float s_MI[2];
  const int hb = blockIdx.x;          // h*64 + b
  const int h = hb >> 6, b = hb & 63;
  const int tid = threadIdx.x;
  const int lane = tid & 63;
  const int count = min(counts[b], IDX_STRIDE);
  const int nsl = min((count + WSL_S - 1) / WSL_S, NSL);

  // ---- combine (m,l) over slices: tid<128 each owns one slice, 2-wave reduce
  {
    float m = -INFINITY, l = 0.f;
    if (tid < nsl) {
      m = ml_ws[(((size_t)b * NSL + tid) * NH + h) * 2 + 0];
      l = ml_ws[(((size_t)b * NSL + tid) * NH + h) * 2 + 1];
    }
    #pragma unroll
    for (int off = 32; off > 0; off >>= 1) {
      const float mo = __shfl_xor(m, off);
      const float lo = __shfl_xor(l, off);
      const float mn = fmaxf(m, mo);
      if (mn == -INFINITY) { l = 0.f; }
      else { l = l * __expf(m - mn) + lo * __expf(mo - mn); }
      m = mn;
    }
    if (tid < 128 && lane == 0) { s_mw[tid >> 6][0] = m; s_mw[tid >> 6][1] = l; }
    __syncthreads();
    if (tid == 0) {
      float M = s_mw[0][0], L = s_mw[0][1];
      const float m2 = s_mw[1][0], l2 = s_mw[1][1];
      const float Mn = fmaxf(M, m2);
      if (Mn == -INFINITY) { L = 0.f; }
      else { L = L * __expf(M - Mn) + l2 * __expf(m2 - Mn); }
      s_MI[0] = Mn;
      s_MI[1] = (L > 0.f) ? 1.f / L : 0.f;
    }
    __syncthreads();
  }
  const float M = s_MI[0], inv = s_MI[1];

  // ---- compact weights w2[b][j][h] (coalesced: tid -> (j=tid>>3, h'=tid&7))
  {
    const int hh = tid & 7;
    for (int jb = 0; jb < IDX_STRIDE; jb += 32) {
      const int j = jb + (tid >> 3);
      if (j >= count) break;
      if (hh == h)
        w2[((size_t)b * IDX_STRIDE + j) * NH + h] =
            __expf(score2[((size_t)b * IDX_STRIDE + j) * NH + h] - M) * inv;
    }
  }

  // ---- dense zero + barrier + scatter
  float* __restrict__ arow = attn_out + (size_t)hb * NE;
  float4* __restrict__ arow4 = (float4*)arow;
  const float4 z4 = {0.f, 0.f, 0.f, 0.f};
  for (int c = tid; c < NE / 4; c += 256) arow4[c] = z4;
  __syncthreads();   // drains vmcnt -> zeros committed before scatter

  const int* __restrict__ myidx = idx + b * IDX_STRIDE;
  for (int j = tid; j < count; j += 256)
    arow[myidx[j]] =
        __expf(score2[((size_t)b * IDX_STRIDE + j) * NH + h] - M) * inv;
}

// ============ agg: wave = 32 keys; weights read from w2 (no exp); block partial
__global__ __launch_bounds__(256) void agg_k(const float* __restrict__ lv,
    const int* __restrict__ idx, const int* __restrict__ counts,
    const float* __restrict__ w2, float* __restrict__ pagg)
{
  __shared__ float s_red[3][NH][260];
  const int b = blockIdx.x >> 4;
  const int blk = blockIdx.x & 15;
  const int tid = threadIdx.x;
  const int wid = tid >> 6, lane = tid & 63;
  const int count = min(counts[b], IDX_STRIDE);
  if (blk * 128 >= count) return;               // whole-block uniform exit

  const int j0 = (blk * 4 + wid) * WSLICE;
  const int nk = min(WSLICE, count - j0);       // may be <= 0

  float4 acc[NH];
  #pragma unroll
  for (int h = 0; h < NH; ++h) acc[h] = (float4){0.f, 0.f, 0.f, 0.f};

  if (nk > 0) {
    const int eidx = (lane < nk) ? idx[b * IDX_STRIDE + j0 + lane] : 0;
    #pragma unroll 2
    for (int t = 0; t < nk; ++t) {
      const int e = __shfl(eidx, t);
      const float4 x4 = *(const float4*)(lv + (size_t)e * ND + lane * 4);
      const float4 wlo = *(const float4*)(w2 + ((size_t)b * IDX_STRIDE + j0 + t) * NH);
      const float4 whi = *(const float4*)(w2 + ((size_t)b * IDX_STRIDE + j0 + t) * NH + 4);
      const float wv[8] = {wlo.x, wlo.y, wlo.z, wlo.w, whi.x, whi.y, whi.z, whi.w};
      #pragma unroll
      for (int h = 0; h < NH; ++h) {
        acc[h].x = fmaf(wv[h], x4.x, acc[h].x);
        acc[h].y = fmaf(wv[h], x4.y, acc[h].y);
        acc[h].z = fmaf(wv[h], x4.z, acc[h].z);
        acc[h].w = fmaf(wv[h], x4.w, acc[h].w);
      }
    }
  }

  if (wid != 0) {
    #pragma unroll
    for (int h = 0; h < NH; ++h)
      *(float4*)&s_red[wid - 1][h][lane * 4] = acc[h];
  }
  __syncthreads();
  if (wid == 0) {
    #pragma unroll
    for (int h = 0; h < NH; ++h) {
      #pragma unroll
      for (int w = 0; w < 3; ++w) {
        const float4 r = *(const float4*)&s_red[w][h][lane * 4];
        acc[h].x += r.x; acc[h].y += r.y; acc[h].z += r.z; acc[h].w += r.w;
      }
    }
    float* pb = pagg + (((size_t)b * NPB + blk) * NH) * ND;
    #pragma unroll
    for (int h = 0; h < NH; ++h)
      *(float4*)(pb + h * ND + lane * 4) = acc[h];
  }
}

// ============ final: sum used block-partials, apply Wv (+bv), then Wo (+bo)
__global__ __launch_bounds__(256) void final_k(const float* __restrict__ pagg,
    const int* __restrict__ counts, const float* __restrict__ Wv,
    const float* __restrict__ bv, const float* __restrict__ Wo,
    const float* __restrict__ bo, float* __restrict__ xout)
{
  __shared__ float agg[NH][260];
  __shared__ float opre[ND];
  const int b = blockIdx.x;
  const int tid = threadIdx.x;
  const int count = min(counts[b], IDX_STRIDE);
  const int nblk = min((count + 127) / 128, NPB);

  #pragma unroll
  for (int h = 0; h < NH; ++h) {
    float a = 0.f;
    for (int s = 0; s < nblk; ++s)
      a += pagg[(((size_t)b * NPB + s) * NH + h) * ND + tid];
    agg[h][tid] = a;
  }
  const float ind = (count > 0) ? 1.f : 0.f;
  __syncthreads();

  {
    const int h = tid >> 5;
    float acc = bv[tid] * ind;
    const float4* wp = (const float4*)(Wv + (size_t)tid * ND);
    #pragma unroll 8
    for (int d4 = 0; d4 < ND / 4; ++d4) {
      float4 w = wp[d4];
      float4 g = *(const float4*)&agg[h][4 * d4];
      acc = fmaf(w.x, g.x, acc);
      acc = fmaf(w.y, g.y, acc);
      acc = fmaf(w.z, g.z, acc);
      acc = fmaf(w.w, g.w, acc);
    }
    opre[tid] = acc;
  }
  __syncthreads();
  {
    float acc = bo[tid];
    const float4* wp = (const float4*)(Wo + (size_t)tid * ND);
    #pragma unroll 8
    for (int d4 = 0; d4 < ND / 4; ++d4) {
      float4 w = wp[d4];
      float4 g = *(const float4*)&opre[4 * d4];
      acc = fmaf(w.x, g.x, acc);
      acc = fmaf(w.y, g.y, acc);
      acc = fmaf(w.z, g.z, acc);
      acc = fmaf(w.w, g.w, acc);
    }
    xout[(size_t)b * ND + tid] = acc;
  }
}

extern "C" void kernel_launch(void* const* d_in, const int* in_sizes, int n_in,
                              void* d_out, int out_size, void* d_ws, size_t ws_size,
                              hipStream_t stream)
{
  const float* gq   = (const float*)d_in[0];
  const float* lk   = (const float*)d_in[1];
  const float* lv   = (const float*)d_in[2];
  const int*  batch = (const int*)d_in[3];
  const float* Wq = (const float*)d_in[4];
  const float* bq = (const float*)d_in[5];
  const float* Wk = (const float*)d_in[6];
  const float* bk = (const float*)d_in[7];
  const float* Wv = (const float*)d_in[8];
  const float* bv = (const float*)d_in[9];
  const float* Wo = (const float*)d_in[10];
  const float* bo = (const float*)d_in[11];

  float* xout = (float*)d_out;                          // [64,256]
  float* attn_out = xout + (size_t)NB * ND;             // [H,B,E]

  float* t2      = (float*)d_ws;                                    // 64*256*8
  float* c_ws    = t2 + (size_t)NB * ND * NH;                       // 512
  float* score2  = c_ws + (size_t)NB * NH;                          // 64*2048*8
  float* ml_ws   = score2 + (size_t)NB * IDX_STRIDE * NH;           // 64*128*8*2
  float* w2      = ml_ws + (size_t)NB * NSL * NH * 2;               // 64*2048*8
  float* pagg    = w2 + (size_t)NB * IDX_STRIDE * NH;               // 64*16*8*256
  int*   idx     = (int*)(pagg + (size_t)NB * NPB * NH * ND);       // 64*2048
  int*   counts  = idx + (size_t)NB * IDX_STRIDE;                   // 64

  prep_k<<<NB, ND, 0, stream>>>(gq, Wq, bq, Wk, bk, t2, c_ws);
  bucket_k<<<NB, 256, 0, stream>>>(batch, idx, counts);
  score_k<<<NB * 32, 256, 0, stream>>>(lk, idx, counts, t2, c_ws, score2, ml_ws);
  attn_write_k<<<NH * NB, 256, 0, stream>>>(score2, ml_ws, idx, counts, w2, attn_out);
  agg_k<<<NB * 16, 256, 0, stream>>>(lv, idx, counts, w2, pagg);
  final_k<<<NB, 256, 0, stream>>>(pagg, counts, Wv, bv, Wo, bo, xout);
}

// Round 10
// 184.094 us; speedup vs baseline: 1.4436x; 1.0699x over previous
//
#include <hip/hip_runtime.h>
#include <hip/hip_bf16.h>
#include <math.h>

#define NB 64        // B
#define NH 8         // H
#define NE 65536     // E
#define ND 256       // N2
#define IDX_STRIDE 2048
#define WSL 16       // keys per wave in score_agg
#define NPB 32       // blocks (partials) per b: 64 keys/block

// ============ k1: fused prep (blocks 0-63) + bucket (blocks 64-127)
__global__ __launch_bounds__(256) void prep_bucket_k(const float* __restrict__ gq,
    const float* __restrict__ Wq, const float* __restrict__ bq,
    const float* __restrict__ Wk, const float* __restrict__ bk,
    const int* __restrict__ batch,
    float* __restrict__ t2, float* __restrict__ c_ws,
    int* __restrict__ idx, int* __restrict__ counts)
{
  __shared__ float xs[ND];
  __shared__ float qs[ND];
  __shared__ int sc[256];
  const int tid = threadIdx.x;

  if (blockIdx.x < 64) {
    // ---- prep: q = Wq gq + bq ; t2[b][d][h] = (Wk_h^T q_h)[d] ; c[h]=q_h.bk_h
    const int b = blockIdx.x;
    const int j = tid;
    xs[j] = gq[(size_t)b * ND + j];
    __syncthreads();
    float acc = bq[j];
    const float4* wp = (const float4*)(Wq + (size_t)j * ND);
    #pragma unroll 8
    for (int k4 = 0; k4 < ND / 4; ++k4) {
      float4 w = wp[k4];
      float4 x = *(const float4*)&xs[k4 * 4];
      acc = fmaf(x.x, w.x, acc);
      acc = fmaf(x.y, w.y, acc);
      acc = fmaf(x.z, w.z, acc);
      acc = fmaf(x.w, w.w, acc);
    }
    qs[j] = acc;
    __syncthreads();
    float th[NH];
    #pragma unroll
    for (int h = 0; h < NH; ++h) th[h] = 0.f;
    #pragma unroll
    for (int h = 0; h < NH; ++h) {
      #pragma unroll 8
      for (int dd = 0; dd < 32; ++dd)
        th[h] = fmaf(qs[h * 32 + dd], Wk[(size_t)(h * 32 + dd) * ND + j], th[h]);
    }
    float* tp = t2 + ((size_t)b * ND + j) * NH;
    #pragma unroll
    for (int h = 0; h < NH; ++h) tp[h] = th[h];
    if (j < NH) {
      float c = 0.f;
      #pragma unroll
      for (int dd = 0; dd < 32; ++dd)
        c = fmaf(qs[j * 32 + dd], bk[j * 32 + dd], c);
      c_ws[b * NH + j] = c;
    }
  } else {
    // ---- bucket: thread-owns-256-keys + block scan; sorted output
    const int b = blockIdx.x - 64;
    const int4* b4 = (const int4*)batch;
    int c = 0;
    #pragma unroll 4
    for (int i = 0; i < 64; ++i) {
      const int4 v = b4[tid * 64 + i];
      c += (v.x == b) + (v.y == b) + (v.z == b) + (v.w == b);
    }
    sc[tid] = c;
    __syncthreads();
    for (int s = 1; s < 256; s <<= 1) {
      const int t = (tid >= s) ? sc[tid - s] : 0;
      __syncthreads();
      sc[tid] += t;
      __syncthreads();
    }
    int pos = sc[tid] - c;
    int* __restrict__ myidx = idx + b * IDX_STRIDE;
    #pragma unroll 4
    for (int i = 0; i < 64; ++i) {
      const int4 v = b4[tid * 64 + i];
      const int e0 = tid * 256 + i * 4;
      if (v.x == b) { if (pos < IDX_STRIDE) myidx[pos] = e0 + 0; ++pos; }
      if (v.y == b) { if (pos < IDX_STRIDE) myidx[pos] = e0 + 1; ++pos; }
      if (v.z == b) { if (pos < IDX_STRIDE) myidx[pos] = e0 + 2; ++pos; }
      if (v.w == b) { if (pos < IDX_STRIDE) myidx[pos] = e0 + 3; ++pos; }
    }
    if (tid == 255) counts[b] = sc[255];
  }
}

// ============ k2: fused score+aggregate. Wave = 16 keys; block = 64 keys.
// Per key: gather lk row (scores, 8 heads via shuffles) + lv row (flash-style
// online aggregate with wave-uniform rescale). Block-reduce 4 waves -> one
// partial (acc, m, l) per block: pagg[b][blk][h][256], ml_ws[b][blk][h].
__global__ __launch_bounds__(256) void score_agg_k(const float* __restrict__ lk,
    const float* __restrict__ lv, const int* __restrict__ idx,
    const int* __restrict__ counts, const float* __restrict__ t2,
    const float* __restrict__ c_ws, float* __restrict__ score2,
    float* __restrict__ ml_ws, float* __restrict__ pagg)
{
  __shared__ float s_acc[3][NH][260];
  __shared__ float s_ml[3][NH][2];
  const int b = blockIdx.x >> 5;
  const int blk = blockIdx.x & 31;
  const int tid = threadIdx.x;
  const int wid = tid >> 6, lane = tid & 63;
  const int count = min(counts[b], IDX_STRIDE);
  if (blk * 64 >= count) return;                // block-uniform exit
  const int j0 = (blk * 4 + wid) * WSL;
  const int nk = min(WSL, count - j0);          // may be <= 0 for wid>0

  float t2s[32];
  {
    const float4* tp = (const float4*)(t2 + ((size_t)b * ND + lane * 4) * NH);
    #pragma unroll
    for (int k = 0; k < 8; ++k) {
      float4 v = tp[k];
      t2s[4 * k + 0] = v.x; t2s[4 * k + 1] = v.y;
      t2s[4 * k + 2] = v.z; t2s[4 * k + 3] = v.w;
    }
  }
  const float c8 = c_ws[b * NH + (lane & 7)];
  const int eidx = (lane < nk) ? idx[b * IDX_STRIDE + j0 + lane] : 0;

  float m8[NH], l8[NH];
  float4 acc[NH];
  #pragma unroll
  for (int h = 0; h < NH; ++h) {
    m8[h] = -INFINITY; l8[h] = 0.f;
    acc[h] = (float4){0.f, 0.f, 0.f, 0.f};
  }

  for (int t = 0; t < nk; ++t) {
    const int e = __shfl(eidx, t);
    const float4 x4 = *(const float4*)(lk + (size_t)e * ND + lane * 4);
    const float4 y4 = *(const float4*)(lv + (size_t)e * ND + lane * 4);
    // scores: 8 partial dots per lane over its 4 dims
    float p[8];
    #pragma unroll
    for (int h = 0; h < 8; ++h)
      p[h] = fmaf(x4.x, t2s[0 * 8 + h], 0.f);
    #pragma unroll
    for (int h = 0; h < 8; ++h) {
      p[h] = fmaf(x4.y, t2s[1 * 8 + h], p[h]);
      p[h] = fmaf(x4.z, t2s[2 * 8 + h], p[h]);
      p[h] = fmaf(x4.w, t2s[3 * 8 + h], p[h]);
    }
    #pragma unroll
    for (int h = 0; h < 8; ++h) {
      p[h] += __shfl_xor(p[h], 1);
      p[h] += __shfl_xor(p[h], 2);
      p[h] += __shfl_xor(p[h], 4);
    }
    float v = p[0];
    #pragma unroll
    for (int h = 1; h < 8; ++h) v = ((lane & 7) == h) ? p[h] : v;
    v += __shfl_xor(v, 8);
    v += __shfl_xor(v, 16);
    v += __shfl_xor(v, 32);
    v += c8;                                    // lane holds s for h=lane&7
    if (lane < 8)
      score2[((size_t)b * IDX_STRIDE + j0 + t) * NH + lane] = v;
    // broadcast all 8 head-scores to every lane
    float s_all[8];
    #pragma unroll
    for (int h = 0; h < 8; ++h) s_all[h] = __shfl(v, h);
    // online aggregate; rescale branch is wave-uniform (s_all uniform)
    #pragma unroll
    for (int h = 0; h < 8; ++h) {
      const float sh = s_all[h];
      const float mn = fmaxf(m8[h], sh);
      const float w = __expf(sh - mn);
      if (mn > m8[h]) {
        const float r = __expf(m8[h] - mn);     // first iter: exp(-inf)=0
        l8[h] = l8[h] * r + w;
        acc[h].x *= r; acc[h].y *= r; acc[h].z *= r; acc[h].w *= r;
        m8[h] = mn;
      } else {
        l8[h] += w;
      }
      acc[h].x = fmaf(w, y4.x, acc[h].x);
      acc[h].y = fmaf(w, y4.y, acc[h].y);
      acc[h].z = fmaf(w, y4.z, acc[h].z);
      acc[h].w = fmaf(w, y4.w, acc[h].w);
    }
  }

  // block reduce across 4 waves with rescale
  if (wid != 0) {
    #pragma unroll
    for (int h = 0; h < NH; ++h)
      *(float4*)&s_acc[wid - 1][h][lane * 4] = acc[h];
    if (lane == 0) {
      #pragma unroll
      for (int h = 0; h < NH; ++h) {
        s_ml[wid - 1][h][0] = m8[h];
        s_ml[wid - 1][h][1] = l8[h];
      }
    }
  }
  __syncthreads();
  if (wid == 0) {
    #pragma unroll
    for (int h = 0; h < NH; ++h) {
      float Mb = m8[h];
      #pragma unroll
      for (int w = 0; w < 3; ++w) Mb = fmaxf(Mb, s_ml[w][h][0]);
      const float r0 = __expf(m8[h] - Mb);      // empty wave: exp(-inf)=0
      float4 a;
      a.x = acc[h].x * r0; a.y = acc[h].y * r0;
      a.z = acc[h].z * r0; a.w = acc[h].w * r0;
      float lb = l8[h] * r0;
      #pragma unroll
      for (int w = 0; w < 3; ++w) {
        const float rw = __expf(s_ml[w][h][0] - Mb);
        lb = fmaf(s_ml[w][h][1], rw, lb);
        const float4 aw = *(const float4*)&s_acc[w][h][lane * 4];
        a.x = fmaf(aw.x, rw, a.x); a.y = fmaf(aw.y, rw, a.y);
        a.z = fmaf(aw.z, rw, a.z); a.w = fmaf(aw.w, rw, a.w);
      }
      *(float4*)(pagg + (((size_t)b * NPB + blk) * NH + h) * ND + lane * 4) = a;
      if (lane == 0) {
        ml_ws[(((size_t)b * NPB + blk) * NH + h) * 2 + 0] = Mb;
        ml_ws[(((size_t)b * NPB + blk) * NH + h) * 2 + 1] = lb;
      }
    }
  }
}

// ============ k3: combine per-block (m,l) -> Minv[b][h] + scale[b][blk][h]
__global__ __launch_bounds__(256) void combine_k(const float* __restrict__ ml_ws,
    const int* __restrict__ counts, float* __restrict__ Minv_ws,
    float* __restrict__ scale_ws)
{
  const int b = blockIdx.x;
  const int tid = threadIdx.x;
  const int h = tid >> 5, i = tid & 31;       // one (h, blk) per thread
  const int count = min(counts[b], IDX_STRIDE);
  const int nblk = min((count + 63) / 64, NPB);

  float m = -INFINITY, l = 0.f;
  float mi = -INFINITY;
  if (i < nblk) {
    mi = ml_ws[(((size_t)b * NPB + i) * NH + h) * 2 + 0];
    l = ml_ws[(((size_t)b * NPB + i) * NH + h) * 2 + 1];
    m = mi;
  }
  // xor butterfly over the 32-group: every lane ends with combined (M,L)
  #pragma unroll
  for (int off = 1; off <= 16; off <<= 1) {
    const float mo = __shfl_xor(m, off);
    const float lo = __shfl_xor(l, off);
    const float mn = fmaxf(m, mo);
    if (mn == -INFINITY) { l = 0.f; }
    else { l = l * __expf(m - mn) + lo * __expf(mo - mn); }
    m = mn;
  }
  const float inv = (l > 0.f) ? 1.f / l : 0.f;
  scale_ws[((size_t)b * NPB + i) * NH + h] =
      (i < nblk) ? __expf(mi - m) * inv : 0.f;
  if (i == 0) {
    Minv_ws[((size_t)b * NH + h) * 2 + 0] = m;
    Minv_ws[((size_t)b * NH + h) * 2 + 1] = inv;
  }
}

// ============ k4: attn_write: zero stream + one barrier + L2-hot scatter
__global__ __launch_bounds__(256) void attn_write_k(
    const float* __restrict__ score2, const float* __restrict__ Minv_ws,
    const int* __restrict__ idx, const int* __restrict__ counts,
    float* __restrict__ attn_out)
{
  const int hb = blockIdx.x;          // h*64 + b
  const int h = hb >> 6, b = hb & 63;
  const int tid = threadIdx.x;
  const int count = min(counts[b], IDX_STRIDE);

  const float M = Minv_ws[((size_t)b * NH + h) * 2 + 0];
  const float inv = Minv_ws[((size_t)b * NH + h) * 2 + 1];

  float* __restrict__ arow = attn_out + (size_t)hb * NE;
  float4* __restrict__ arow4 = (float4*)arow;
  const float4 z4 = {0.f, 0.f, 0.f, 0.f};
  for (int c = tid; c < NE / 4; c += 256) arow4[c] = z4;
  __syncthreads();   // drains vmcnt -> zeros committed before scatter

  const int* __restrict__ myidx = idx + b * IDX_STRIDE;
  for (int j = tid; j < count; j += 256)
    arow[myidx[j]] =
        __expf(score2[((size_t)b * IDX_STRIDE + j) * NH + h] - M) * inv;
}

// ============ k5: final: agg = sum_blk pagg*scale; Wv (+bv*ind); Wo (+bo)
__global__ __launch_bounds__(256) void final_k(const float* __restrict__ pagg,
    const float* __restrict__ scale_ws, const int* __restrict__ counts,
    const float* __restrict__ Wv, const float* __restrict__ bv,
    const float* __restrict__ Wo, const float* __restrict__ bo,
    float* __restrict__ xout)
{
  __shared__ float s_scale[NH][NPB];
  __shared__ float agg[NH][260];
  __shared__ float opre[ND];
  const int b = blockIdx.x;
  const int tid = threadIdx.x;
  const int count = min(counts[b], IDX_STRIDE);
  const int nblk = min((count + 63) / 64, NPB);

  {
    const int h = tid >> 5, i = tid & 31;
    s_scale[h][i] = scale_ws[((size_t)b * NPB + i) * NH + h];
  }
  __syncthreads();

  #pragma unroll
  for (int h = 0; h < NH; ++h) {
    float a = 0.f;
    for (int s = 0; s < nblk; ++s)
      a = fmaf(pagg[(((size_t)b * NPB + s) * NH + h) * ND + tid],
               s_scale[h][s], a);
    agg[h][tid] = a;
  }
  const float ind = (count > 0) ? 1.f : 0.f;
  __syncthreads();

  {
    const int h = tid >> 5;
    float acc = bv[tid] * ind;
    const float4* wp = (const float4*)(Wv + (size_t)tid * ND);
    #pragma unroll 8
    for (int d4 = 0; d4 < ND / 4; ++d4) {
      float4 w = wp[d4];
      float4 g = *(const float4*)&agg[h][4 * d4];
      acc = fmaf(w.x, g.x, acc);
      acc = fmaf(w.y, g.y, acc);
      acc = fmaf(w.z, g.z, acc);
      acc = fmaf(w.w, g.w, acc);
    }
    opre[tid] = acc;
  }
  __syncthreads();
  {
    float acc = bo[tid];
    const float4* wp = (const float4*)(Wo + (size_t)tid * ND);
    #pragma unroll 8
    for (int d4 = 0; d4 < ND / 4; ++d4) {
      float4 w = wp[d4];
      float4 g = *(const float4*)&opre[4 * d4];
      acc = fmaf(w.x, g.x, acc);
      acc = fmaf(w.y, g.y, acc);
      acc = fmaf(w.z, g.z, acc);
      acc = fmaf(w.w, g.w, acc);
    }
    xout[(size_t)b * ND + tid] = acc;
  }
}

extern "C" void kernel_launch(void* const* d_in, const int* in_sizes, int n_in,
                              void* d_out, int out_size, void* d_ws, size_t ws_size,
                              hipStream_t stream)
{
  const float* gq   = (const float*)d_in[0];
  const float* lk   = (const float*)d_in[1];
  const float* lv   = (const float*)d_in[2];
  const int*  batch = (const int*)d_in[3];
  const float* Wq = (const float*)d_in[4];
  const float* bq = (const float*)d_in[5];
  const float* Wk = (const float*)d_in[6];
  const float* bk = (const float*)d_in[7];
  const float* Wv = (const float*)d_in[8];
  const float* bv = (const float*)d_in[9];
  const float* Wo = (const float*)d_in[10];
  const float* bo = (const float*)d_in[11];

  float* xout = (float*)d_out;                          // [64,256]
  float* attn_out = xout + (size_t)NB * ND;             // [H,B,E]

  float* t2       = (float*)d_ws;                                   // 64*256*8
  float* c_ws     = t2 + (size_t)NB * ND * NH;                      // 512
  float* score2   = c_ws + (size_t)NB * NH;                         // 64*2048*8
  float* ml_ws    = score2 + (size_t)NB * IDX_STRIDE * NH;          // 64*32*8*2
  float* scale_ws = ml_ws + (size_t)NB * NPB * NH * 2;              // 64*32*8
  float* Minv_ws  = scale_ws + (size_t)NB * NPB * NH;               // 64*8*2
  float* pagg     = Minv_ws + (size_t)NB * NH * 2;                  // 64*32*8*256
  int*   idx      = (int*)(pagg + (size_t)NB * NPB * NH * ND);      // 64*2048
  int*   counts   = idx + (size_t)NB * IDX_STRIDE;                  // 64

  prep_bucket_k<<<128, 256, 0, stream>>>(gq, Wq, bq, Wk, bk, batch,
                                         t2, c_ws, idx, counts);
  score_agg_k<<<NB * NPB, 256, 0, stream>>>(lk, lv, idx, counts, t2, c_ws,
                                            score2, ml_ws, pagg);
  combine_k<<<NB, 256, 0, stream>>>(ml_ws, counts, Minv_ws, scale_ws);
  attn_write_k<<<NH * NB, 256, 0, stream>>>(score2, Minv_ws, idx, counts, attn_out);
  final_k<<<NB, 256, 0, stream>>>(pagg, scale_ws, counts, Wv, bv, Wo, bo, xout);
}

// Round 11
// 163.780 us; speedup vs baseline: 1.6227x; 1.1240x over previous
//
#include <hip/hip_runtime.h>
#include <hip/hip_bf16.h>
#include <math.h>

#define NB 64        // B
#define NH 8         // H
#define NE 65536     // E
#define ND 256       // N2
#define IDX_STRIDE 2048
#define WSL 16       // keys per wave in score_agg
#define NPB 32       // blocks (partials) per b: 64 keys/block

// ============ k1: fused prep (blocks 0-63) + bucket (blocks 64-127)
__global__ __launch_bounds__(256) void prep_bucket_k(const float* __restrict__ gq,
    const float* __restrict__ Wq, const float* __restrict__ bq,
    const float* __restrict__ Wk, const float* __restrict__ bk,
    const int* __restrict__ batch,
    float* __restrict__ t2, float* __restrict__ c_ws,
    int* __restrict__ idx, int* __restrict__ counts)
{
  __shared__ float xs[ND];
  __shared__ float qs[ND];
  __shared__ int sc[256];
  const int tid = threadIdx.x;

  if (blockIdx.x < 64) {
    const int b = blockIdx.x;
    const int j = tid;
    xs[j] = gq[(size_t)b * ND + j];
    __syncthreads();
    float acc = bq[j];
    const float4* wp = (const float4*)(Wq + (size_t)j * ND);
    #pragma unroll 8
    for (int k4 = 0; k4 < ND / 4; ++k4) {
      float4 w = wp[k4];
      float4 x = *(const float4*)&xs[k4 * 4];
      acc = fmaf(x.x, w.x, acc);
      acc = fmaf(x.y, w.y, acc);
      acc = fmaf(x.z, w.z, acc);
      acc = fmaf(x.w, w.w, acc);
    }
    qs[j] = acc;
    __syncthreads();
    float th[NH];
    #pragma unroll
    for (int h = 0; h < NH; ++h) th[h] = 0.f;
    #pragma unroll
    for (int h = 0; h < NH; ++h) {
      #pragma unroll 8
      for (int dd = 0; dd < 32; ++dd)
        th[h] = fmaf(qs[h * 32 + dd], Wk[(size_t)(h * 32 + dd) * ND + j], th[h]);
    }
    float* tp = t2 + ((size_t)b * ND + j) * NH;
    #pragma unroll
    for (int h = 0; h < NH; ++h) tp[h] = th[h];
    if (j < NH) {
      float c = 0.f;
      #pragma unroll
      for (int dd = 0; dd < 32; ++dd)
        c = fmaf(qs[j * 32 + dd], bk[j * 32 + dd], c);
      c_ws[b * NH + j] = c;
    }
  } else {
    const int b = blockIdx.x - 64;
    const int4* b4 = (const int4*)batch;
    int c = 0;
    #pragma unroll 4
    for (int i = 0; i < 64; ++i) {
      const int4 v = b4[tid * 64 + i];
      c += (v.x == b) + (v.y == b) + (v.z == b) + (v.w == b);
    }
    sc[tid] = c;
    __syncthreads();
    for (int s = 1; s < 256; s <<= 1) {
      const int t = (tid >= s) ? sc[tid - s] : 0;
      __syncthreads();
      sc[tid] += t;
      __syncthreads();
    }
    int pos = sc[tid] - c;
    int* __restrict__ myidx = idx + b * IDX_STRIDE;
    #pragma unroll 4
    for (int i = 0; i < 64; ++i) {
      const int4 v = b4[tid * 64 + i];
      const int e0 = tid * 256 + i * 4;
      if (v.x == b) { if (pos < IDX_STRIDE) myidx[pos] = e0 + 0; ++pos; }
      if (v.y == b) { if (pos < IDX_STRIDE) myidx[pos] = e0 + 1; ++pos; }
      if (v.z == b) { if (pos < IDX_STRIDE) myidx[pos] = e0 + 2; ++pos; }
      if (v.w == b) { if (pos < IDX_STRIDE) myidx[pos] = e0 + 3; ++pos; }
    }
    if (tid == 255) counts[b] = sc[255];
  }
}

// ============ k2: fused score+aggregate, phase-split.
// Wave = 16 keys; lane holds score/weight of head (lane&7) per key in regs.
// Phase 1: scores (pipelined lk gathers, halving-butterfly reduce).
// Mid: per-lane max + 16 lane-parallel exp (no online-softmax chain).
// Phase 2: PV aggregate (pipelined lv gathers, 8 w-broadcasts/key).
__global__ __launch_bounds__(256) void score_agg_k(const float* __restrict__ lk,
    const float* __restrict__ lv, const int* __restrict__ idx,
    const int* __restrict__ counts, const float* __restrict__ t2,
    const float* __restrict__ c_ws, float* __restrict__ score2,
    float* __restrict__ ml_ws, float* __restrict__ pagg)
{
  __shared__ float s_acc[3][NH][260];
  __shared__ float s_mlb[4][NH][2];
  const int b = blockIdx.x >> 5;
  const int blk = blockIdx.x & 31;
  const int tid = threadIdx.x;
  const int wid = tid >> 6, lane = tid & 63;
  const int count = min(counts[b], IDX_STRIDE);
  if (blk * 64 >= count) return;                // block-uniform exit
  const int j0 = (blk * 4 + wid) * WSL;
  const int nk = min(WSL, count - j0);          // may be <= 0 for wid>0

  float t2s[32];
  {
    const float4* tp = (const float4*)(t2 + ((size_t)b * ND + lane * 4) * NH);
    #pragma unroll
    for (int k = 0; k < 8; ++k) {
      float4 v = tp[k];
      t2s[4 * k + 0] = v.x; t2s[4 * k + 1] = v.y;
      t2s[4 * k + 2] = v.z; t2s[4 * k + 3] = v.w;
    }
  }
  const float c8 = c_ws[b * NH + (lane & 7)];
  const int eidx = (lane < nk) ? idx[b * IDX_STRIDE + j0 + lane] : 0;

  float sw[WSL];                 // scores, later overwritten with weights
  float m = -INFINITY, l = 0.f;

  // ---------- phase 1: scores
  {
    float4 xp0, xp1;
    if (nk > 0) xp0 = *(const float4*)(lk + (size_t)__shfl(eidx, 0) * ND + lane * 4);
    if (nk > 1) xp1 = *(const float4*)(lk + (size_t)__shfl(eidx, 1) * ND + lane * 4);
    #pragma unroll
    for (int t = 0; t < WSL; ++t) {
      if (t >= nk) break;
      const float4 x4 = (t & 1) ? xp1 : xp0;
      if (t + 2 < nk) {
        const float4 nx =
            *(const float4*)(lk + (size_t)__shfl(eidx, t + 2) * ND + lane * 4);
        if (t & 1) xp1 = nx; else xp0 = nx;
      }
      float p[8];
      #pragma unroll
      for (int h = 0; h < 8; ++h)
        p[h] = fmaf(x4.x, t2s[0 * 8 + h], 0.f);
      #pragma unroll
      for (int h = 0; h < 8; ++h) {
        p[h] = fmaf(x4.y, t2s[1 * 8 + h], p[h]);
        p[h] = fmaf(x4.z, t2s[2 * 8 + h], p[h]);
        p[h] = fmaf(x4.w, t2s[3 * 8 + h], p[h]);
      }
      // register-halving butterfly: head h lands on lanes with (lane&7)==h
      float q[4];
      #pragma unroll
      for (int i = 0; i < 4; ++i) {
        const float keep = (lane & 4) ? p[i + 4] : p[i];
        const float send = (lane & 4) ? p[i] : p[i + 4];
        q[i] = keep + __shfl_xor(send, 4);
      }
      float u[2];
      #pragma unroll
      for (int i = 0; i < 2; ++i) {
        const float keep = (lane & 2) ? q[i + 2] : q[i];
        const float send = (lane & 2) ? q[i] : q[i + 2];
        u[i] = keep + __shfl_xor(send, 2);
      }
      float v;
      {
        const float keep = (lane & 1) ? u[1] : u[0];
        const float send = (lane & 1) ? u[0] : u[1];
        v = keep + __shfl_xor(send, 1);
      }
      v += __shfl_xor(v, 8);
      v += __shfl_xor(v, 16);
      v += __shfl_xor(v, 32);
      v += c8;                    // complete score for head lane&7, all lanes
      sw[t] = v;
      m = fmaxf(m, v);
      if (lane < 8)
        score2[((size_t)b * IDX_STRIDE + j0 + t) * NH + lane] = v;
    }
  }

  // ---------- weights: lane-parallel exp, per-lane (m,l)
  #pragma unroll
  for (int t = 0; t < WSL; ++t) {
    if (t >= nk) break;
    const float w = __expf(sw[t] - m);
    sw[t] = w;
    l += w;
  }

  // ---------- phase 2: PV aggregate
  float4 acc[NH];
  #pragma unroll
  for (int h = 0; h < NH; ++h) acc[h] = (float4){0.f, 0.f, 0.f, 0.f};
  {
    float4 yp0, yp1;
    if (nk > 0) yp0 = *(const float4*)(lv + (size_t)__shfl(eidx, 0) * ND + lane * 4);
    if (nk > 1) yp1 = *(const float4*)(lv + (size_t)__shfl(eidx, 1) * ND + lane * 4);
    #pragma unroll
    for (int t = 0; t < WSL; ++t) {
      if (t >= nk) break;
      const float4 y4 = (t & 1) ? yp1 : yp0;
      if (t + 2 < nk) {
        const float4 ny =
            *(const float4*)(lv + (size_t)__shfl(eidx, t + 2) * ND + lane * 4);
        if (t & 1) yp1 = ny; else yp0 = ny;
      }
      float wl[8];
      #pragma unroll
      for (int h = 0; h < 8; ++h) wl[h] = __shfl(sw[t], h);
      #pragma unroll
      for (int h = 0; h < 8; ++h) {
        acc[h].x = fmaf(wl[h], y4.x, acc[h].x);
        acc[h].y = fmaf(wl[h], y4.y, acc[h].y);
        acc[h].z = fmaf(wl[h], y4.z, acc[h].z);
        acc[h].w = fmaf(wl[h], y4.w, acc[h].w);
      }
    }
  }

  // ---------- block reduce across 4 waves with rescale
  if (lane < 8) {
    s_mlb[wid][lane][0] = m;
    s_mlb[wid][lane][1] = l;
  }
  if (wid != 0) {
    #pragma unroll
    for (int h = 0; h < NH; ++h)
      *(float4*)&s_acc[wid - 1][h][lane * 4] = acc[h];
  }
  __syncthreads();
  if (wid == 0) {
    #pragma unroll
    for (int h = 0; h < NH; ++h) {
      float Mb = s_mlb[0][h][0];            // wave0 nk>=1 -> finite
      #pragma unroll
      for (int w = 1; w < 4; ++w) Mb = fmaxf(Mb, s_mlb[w][h][0]);
      const float r0 = __expf(s_mlb[0][h][0] - Mb);
      float4 a;
      a.x = acc[h].x * r0; a.y = acc[h].y * r0;
      a.z = acc[h].z * r0; a.w = acc[h].w * r0;
      float lb = s_mlb[0][h][1] * r0;
      #pragma unroll
      for (int w = 1; w < 4; ++w) {
        const float rw = __expf(s_mlb[w][h][0] - Mb);   // -inf -> 0 (empty)
        lb = fmaf(s_mlb[w][h][1], rw, lb);
        const float4 aw = *(const float4*)&s_acc[w - 1][h][lane * 4];
        a.x = fmaf(aw.x, rw, a.x); a.y = fmaf(aw.y, rw, a.y);
        a.z = fmaf(aw.z, rw, a.z); a.w = fmaf(aw.w, rw, a.w);
      }
      *(float4*)(pagg + (((size_t)b * NPB + blk) * NH + h) * ND + lane * 4) = a;
      if (lane == 0) {
        ml_ws[(((size_t)b * NPB + blk) * NH + h) * 2 + 0] = Mb;
        ml_ws[(((size_t)b * NPB + blk) * NH + h) * 2 + 1] = lb;
      }
    }
  }
}

// ============ k3: combine per-block (m,l) -> Minv[b][h] + scale[b][blk][h]
__global__ __launch_bounds__(256) void combine_k(const float* __restrict__ ml_ws,
    const int* __restrict__ counts, float* __restrict__ Minv_ws,
    float* __restrict__ scale_ws)
{
  const int b = blockIdx.x;
  const int tid = threadIdx.x;
  const int h = tid >> 5, i = tid & 31;       // one (h, blk) per thread
  const int count = min(counts[b], IDX_STRIDE);
  const int nblk = min((count + 63) / 64, NPB);

  float m = -INFINITY, l = 0.f;
  float mi = -INFINITY;
  if (i < nblk) {
    mi = ml_ws[(((size_t)b * NPB + i) * NH + h) * 2 + 0];
    l = ml_ws[(((size_t)b * NPB + i) * NH + h) * 2 + 1];
    m = mi;
  }
  #pragma unroll
  for (int off = 1; off <= 16; off <<= 1) {
    const float mo = __shfl_xor(m, off);
    const float lo = __shfl_xor(l, off);
    const float mn = fmaxf(m, mo);
    if (mn == -INFINITY) { l = 0.f; }
    else { l = l * __expf(m - mn) + lo * __expf(mo - mn); }
    m = mn;
  }
  const float inv = (l > 0.f) ? 1.f / l : 0.f;
  scale_ws[((size_t)b * NPB + i) * NH + h] =
      (i < nblk) ? __expf(mi - m) * inv : 0.f;
  if (i == 0) {
    Minv_ws[((size_t)b * NH + h) * 2 + 0] = m;
    Minv_ws[((size_t)b * NH + h) * 2 + 1] = inv;
  }
}

// ============ k4: attn_write: zero stream + one barrier + L2-hot scatter
__global__ __launch_bounds__(256) void attn_write_k(
    const float* __restrict__ score2, const float* __restrict__ Minv_ws,
    const int* __restrict__ idx, const int* __restrict__ counts,
    float* __restrict__ attn_out)
{
  const int hb = blockIdx.x;          // h*64 + b
  const int h = hb >> 6, b = hb & 63;
  const int tid = threadIdx.x;
  const int count = min(counts[b], IDX_STRIDE);

  const float M = Minv_ws[((size_t)b * NH + h) * 2 + 0];
  const float inv = Minv_ws[((size_t)b * NH + h) * 2 + 1];

  float* __restrict__ arow = attn_out + (size_t)hb * NE;
  float4* __restrict__ arow4 = (float4*)arow;
  const float4 z4 = {0.f, 0.f, 0.f, 0.f};
  for (int c = tid; c < NE / 4; c += 256) arow4[c] = z4;
  __syncthreads();   // drains vmcnt -> zeros committed before scatter

  const int* __restrict__ myidx = idx + b * IDX_STRIDE;
  for (int j = tid; j < count; j += 256)
    arow[myidx[j]] =
        __expf(score2[((size_t)b * IDX_STRIDE + j) * NH + h] - M) * inv;
}

// ============ k5: final: agg = sum_blk pagg*scale; Wv (+bv*ind); Wo (+bo)
__global__ __launch_bounds__(256) void final_k(const float* __restrict__ pagg,
    const float* __restrict__ scale_ws, const int* __restrict__ counts,
    const float* __restrict__ Wv, const float* __restrict__ bv,
    const float* __restrict__ Wo, const float* __restrict__ bo,
    float* __restrict__ xout)
{
  __shared__ float s_scale[NH][NPB];
  __shared__ float agg[NH][260];
  __shared__ float opre[ND];
  const int b = blockIdx.x;
  const int tid = threadIdx.x;
  const int count = min(counts[b], IDX_STRIDE);
  const int nblk = min((count + 63) / 64, NPB);

  {
    const int h = tid >> 5, i = tid & 31;
    s_scale[h][i] = scale_ws[((size_t)b * NPB + i) * NH + h];
  }
  __syncthreads();

  #pragma unroll
  for (int h = 0; h < NH; ++h) {
    float a = 0.f;
    for (int s = 0; s < nblk; ++s)
      a = fmaf(pagg[(((size_t)b * NPB + s) * NH + h) * ND + tid],
               s_scale[h][s], a);
    agg[h][tid] = a;
  }
  const float ind = (count > 0) ? 1.f : 0.f;
  __syncthreads();

  {
    const int h = tid >> 5;
    float acc = bv[tid] * ind;
    const float4* wp = (const float4*)(Wv + (size_t)tid * ND);
    #pragma unroll 8
    for (int d4 = 0; d4 < ND / 4; ++d4) {
      float4 w = wp[d4];
      float4 g = *(const float4*)&agg[h][4 * d4];
      acc = fmaf(w.x, g.x, acc);
      acc = fmaf(w.y, g.y, acc);
      acc = fmaf(w.z, g.z, acc);
      acc = fmaf(w.w, g.w, acc);
    }
    opre[tid] = acc;
  }
  __syncthreads();
  {
    float acc = bo[tid];
    const float4* wp = (const float4*)(Wo + (size_t)tid * ND);
    #pragma unroll 8
    for (int d4 = 0; d4 < ND / 4; ++d4) {
      float4 w = wp[d4];
      float4 g = *(const float4*)&opre[4 * d4];
      acc = fmaf(w.x, g.x, acc);
      acc = fmaf(w.y, g.y, acc);
      acc = fmaf(w.z, g.z, acc);
      acc = fmaf(w.w, g.w, acc);
    }
    xout[(size_t)b * ND + tid] = acc;
  }
}

extern "C" void kernel_launch(void* const* d_in, const int* in_sizes, int n_in,
                              void* d_out, int out_size, void* d_ws, size_t ws_size,
                              hipStream_t stream)
{
  const float* gq   = (const float*)d_in[0];
  const float* lk   = (const float*)d_in[1];
  const float* lv   = (const float*)d_in[2];
  const int*  batch = (const int*)d_in[3];
  const float* Wq = (const float*)d_in[4];
  const float* bq = (const float*)d_in[5];
  const float* Wk = (const float*)d_in[6];
  const float* bk = (const float*)d_in[7];
  const float* Wv = (const float*)d_in[8];
  const float* bv = (const float*)d_in[9];
  const float* Wo = (const float*)d_in[10];
  const float* bo = (const float*)d_in[11];

  float* xout = (float*)d_out;                          // [64,256]
  float* attn_out = xout + (size_t)NB * ND;             // [H,B,E]

  float* t2       = (float*)d_ws;                                   // 64*256*8
  float* c_ws     = t2 + (size_t)NB * ND * NH;                      // 512
  float* score2   = c_ws + (size_t)NB * NH;                         // 64*2048*8
  float* ml_ws    = score2 + (size_t)NB * IDX_STRIDE * NH;          // 64*32*8*2
  float* scale_ws = ml_ws + (size_t)NB * NPB * NH * 2;              // 64*32*8
  float* Minv_ws  = scale_ws + (size_t)NB * NPB * NH;               // 64*8*2
  float* pagg     = Minv_ws + (size_t)NB * NH * 2;                  // 64*32*8*256
  int*   idx      = (int*)(pagg + (size_t)NB * NPB * NH * ND);      // 64*2048
  int*   counts   = idx + (size_t)NB * IDX_STRIDE;                  // 64

  prep_bucket_k<<<128, 256, 0, stream>>>(gq, Wq, bq, Wk, bk, batch,
                                         t2, c_ws, idx, counts);
  score_agg_k<<<NB * NPB, 256, 0, stream>>>(lk, lv, idx, counts, t2, c_ws,
                                            score2, ml_ws, pagg);
  combine_k<<<NB, 256, 0, stream>>>(ml_ws, counts, Minv_ws, scale_ws);
  attn_write_k<<<NH * NB, 256, 0, stream>>>(score2, Minv_ws, idx, counts, attn_out);
  final_k<<<NB, 256, 0, stream>>>(pagg, scale_ws, counts, Wv, bv, Wo, bo, xout);
}